// Round 2
// baseline (22859.448 us; speedup 1.0000x reference)
//
#include <hip/hip_runtime.h>

#define BB   8192
#define LEN  40
#define LDN  12
#define PQN  237
#define INN  256
#define HN   64

typedef unsigned int  u32;
typedef unsigned short u16;

__device__ __forceinline__ float sigm(float x){
  return 1.0f / (1.0f + exp2f(-1.44269504f * x));
}
__device__ __forceinline__ float tanhf_(float x){
  x = fminf(15.0f, fmaxf(-15.0f, x));
  float e = exp2f(2.88539008f * x);          // e^(2x)
  return (e - 1.0f) / (e + 1.0f);
}
__device__ __forceinline__ float dot4(float4 w, float4 a){
  return w.x*a.x + w.y*a.y + w.z*a.z + w.w*a.w;
}

// One wave (64 threads) per batch element. Lane d owns h[d], c[d] and gate
// rows {d, 64+d, 128+d, 192+d}. Encoder (40 steps) + decoder (12 steps) fused;
// mid/wd_mid live in LDS (f32, no global workspace).
__global__ __launch_bounds__(64) void stattn_kernel(
    const float* __restrict__ ipq,    // (B,LE,PQ)
    const float* __restrict__ lblp,   // (B,LE)
    const float* __restrict__ e_h,    // (24,5)
    const float* __restrict__ e_w,    // (8,3)
    const float* __restrict__ e_m,    // (13,4)
    const float* __restrict__ e_y,    // (54,7)
    const float* __restrict__ Wi_w,   // (64,256)
    const float* __restrict__ Wi_b,   // (64)
    const float* __restrict__ We_w,   // (64,128)
    const float* __restrict__ Vd_w,   // (256,64)
    const float* __restrict__ Vd_b,   // (256)
    const float* __restrict__ eWih,   // (256,256)
    const float* __restrict__ eWhh,   // (256,64)
    const float* __restrict__ ebih,   // (256)
    const float* __restrict__ ebhh,   // (256)
    const float* __restrict__ Wd_w,   // (64,64)
    const float* __restrict__ Wd_b,   // (64)
    const float* __restrict__ Wd2_w,  // (64,2)
    const float* __restrict__ Vdt_w,  // (1,64)
    const float* __restrict__ Vdt_b,  // (1)
    const float* __restrict__ dWih,   // (4,65)
    const float* __restrict__ dWhh,   // (4,1)
    const float* __restrict__ dbih,   // (4)
    const float* __restrict__ dbhh,   // (4)
    const int* __restrict__ itime,    // (B,LE,4) int32
    float* __restrict__ out)          // (B,LD)
{
  __shared__ __attribute__((aligned(16))) float xs[INN];      // x_t
  __shared__ __attribute__((aligned(16))) float ps[INN];      // x_in
  __shared__ __attribute__((aligned(16))) float us[HN];       // tanh pre-softmax vec
  __shared__ __attribute__((aligned(16))) float hs[HN];
  __shared__ __attribute__((aligned(16))) float cs[HN];
  __shared__ __attribute__((aligned(16))) float ms[LEN * HN]; // mid
  __shared__ __attribute__((aligned(16))) float wm[LEN * HN]; // wd_mid

  const int b = blockIdx.x;
  const int l = threadIdx.x;

  hs[l] = 0.0f; cs[l] = 0.0f;
  float c_d = 0.0f;
  const int ipq_b = b * (LEN * PQN);
  __syncthreads();

  // ---------------- encoder: 40 sequential steps ----------------
  for (int t = 0; t < LEN; ++t) {
    // phase 1: assemble x_t (237 p_q features + 19 embedding features)
    {
      const int tb = (b * LEN + t) * 4;
      const int it0 = itime[tb + 0], it1 = itime[tb + 1];
      const int it2 = itime[tb + 2], it3 = itime[tb + 3];
      #pragma unroll
      for (int j = 0; j < 4; ++j) {
        const int i = l + 64 * j;
        float v;
        if (i < PQN) {
          v = ipq[ipq_b + t * PQN + i];
        } else {
          const int o = i - PQN;
          if      (o < 5 ) v = e_h[it0 * 5 + o];
          else if (o < 8 ) v = e_w[it1 * 3 + (o - 5)];
          else if (o < 12) v = e_m[it2 * 4 + (o - 8)];
          else             v = e_y[it3 * 7 + (o - 12)];
        }
        xs[i] = v;
      }
    }
    __syncthreads();

    // phase 2: u[d] = tanh(Wi_w[d,:]@x + We_w[d,:]@[h;c] + Wi_b[d])
    {
      float acc = Wi_b[l];
      const float4* wr = (const float4*)(Wi_w + l * INN);
      const float4* xv = (const float4*)xs;
      #pragma unroll 8
      for (int k4 = 0; k4 < 64; ++k4)
        acc += dot4(wr[k4], xv[k4]);
      const float4* wr2 = (const float4*)(We_w + l * (2 * HN));
      const float4* hv  = (const float4*)hs;
      const float4* cv  = (const float4*)cs;
      #pragma unroll
      for (int k4 = 0; k4 < 16; ++k4)
        acc += dot4(wr2[k4], hv[k4]);
      #pragma unroll
      for (int k4 = 0; k4 < 16; ++k4)
        acc += dot4(wr2[16 + k4], cv[k4]);
      us[l] = tanhf_(acc);
    }
    __syncthreads();

    // phase 3: score = u @ Vd_w.T + Vd_b ; softmax over 256; x_in = x * p
    {
      float sc[4];
      const float4* uv = (const float4*)us;
      #pragma unroll
      for (int j = 0; j < 4; ++j) {
        const int i = l + 64 * j;
        float acc = Vd_b[i];
        const float4* wr = (const float4*)(Vd_w + i * HN);
        #pragma unroll
        for (int k4 = 0; k4 < 16; ++k4)
          acc += dot4(wr[k4], uv[k4]);
        sc[j] = acc;
      }
      float m = fmaxf(fmaxf(sc[0], sc[1]), fmaxf(sc[2], sc[3]));
      #pragma unroll
      for (int off = 32; off >= 1; off >>= 1) m = fmaxf(m, __shfl_xor(m, off, 64));
      float e0 = exp2f((sc[0] - m) * 1.44269504f);
      float e1 = exp2f((sc[1] - m) * 1.44269504f);
      float e2 = exp2f((sc[2] - m) * 1.44269504f);
      float e3 = exp2f((sc[3] - m) * 1.44269504f);
      float s = e0 + e1 + e2 + e3;
      #pragma unroll
      for (int off = 32; off >= 1; off >>= 1) s += __shfl_xor(s, off, 64);
      const float inv = 1.0f / s;
      ps[l      ] = xs[l      ] * e0 * inv;
      ps[l + 64 ] = xs[l + 64 ] * e1 * inv;
      ps[l + 128] = xs[l + 128] * e2 * inv;
      ps[l + 192] = xs[l + 192] * e3 * inv;
    }
    __syncthreads();

    // phase 4: LSTM gates (rows l, 64+l, 128+l, 192+l) + cell update
    {
      float g[4];
      const float4* pv = (const float4*)ps;
      const float4* hv = (const float4*)hs;
      #pragma unroll
      for (int j = 0; j < 4; ++j) {
        const int row = j * 64 + l;
        float acc = ebih[row] + ebhh[row];
        const float4* wr = (const float4*)(eWih + row * INN);
        #pragma unroll 8
        for (int k4 = 0; k4 < 64; ++k4)
          acc += dot4(wr[k4], pv[k4]);
        const float4* wr2 = (const float4*)(eWhh + row * HN);
        #pragma unroll
        for (int k4 = 0; k4 < 16; ++k4)
          acc += dot4(wr2[k4], hv[k4]);
        g[j] = acc;
      }
      __syncthreads();   // everyone done reading hs before lane-writes
      const float ig = sigm(g[0]);
      const float fg = sigm(g[1]);
      const float gg = tanhf_(g[2]);
      const float og = sigm(g[3]);
      c_d = fg * c_d + ig * gg;
      const float h = og * tanhf_(c_d);
      hs[l] = h;
      cs[l] = c_d;
      ms[t * HN + l] = h;
    }
    __syncthreads();
  }

  // ---------------- decoder ----------------
  // wd_mid[t][d] = Wd_w[d,:] @ mid[t,:] + Wd_b[d]
  {
    float wrow[64];
    const float4* wr = (const float4*)(Wd_w + l * HN);
    #pragma unroll
    for (int k4 = 0; k4 < 16; ++k4) {
      float4 w = wr[k4];
      wrow[4*k4+0] = w.x; wrow[4*k4+1] = w.y; wrow[4*k4+2] = w.z; wrow[4*k4+3] = w.w;
    }
    const float wb = Wd_b[l];
    for (int t = 0; t < LEN; ++t) {
      const float4* mv = (const float4*)(ms + t * HN);
      float acc = wb;
      #pragma unroll
      for (int k4 = 0; k4 < 16; ++k4) {
        float4 mm = mv[k4];
        acc += wrow[4*k4+0]*mm.x + wrow[4*k4+1]*mm.y + wrow[4*k4+2]*mm.z + wrow[4*k4+3]*mm.w;
      }
      wm[t * HN + l] = acc;
    }
  }
  __syncthreads();

  const float dpin = lblp[b * LEN + (LEN - 1)];
  const float w20 = Wd2_w[2 * l];
  const float w21 = Wd2_w[2 * l + 1];
  const float vdt = Vdt_w[l];
  const float vdtb = Vdt_b[0];
  float wih[4], wxx[4], whh[4], bi4[4], bh4[4];
  #pragma unroll
  for (int j = 0; j < 4; ++j) {
    wih[j] = dWih[j * 65 + l];
    wxx[j] = dWih[j * 65 + 64];
    whh[j] = dWhh[j];
    bi4[j] = dbih[j];
    bh4[j] = dbhh[j];
  }

  float hi = 0.0f, ci = 0.0f;
  for (int s = 0; s < LDN; ++s) {
    const float q = w20 * hi + w21 * ci;      // q[d], d = lane
    float ctx = 0.0f;                          // ctx[d]
    for (int t = 0; t < LEN; ++t) {
      float e = tanhf_(q + wm[t * HN + l]) * vdt;
      #pragma unroll
      for (int off = 32; off >= 1; off >>= 1) e += __shfl_xor(e, off, 64);
      const float sct = e + vdtb;              // score[t], all lanes
      ctx += sct * ms[t * HN + l];
    }
    float g4[4];
    #pragma unroll
    for (int j = 0; j < 4; ++j) {
      float p = wih[j] * ctx;
      #pragma unroll
      for (int off = 32; off >= 1; off >>= 1) p += __shfl_xor(p, off, 64);
      g4[j] = p + wxx[j] * dpin + bi4[j] + whh[j] * hi + bh4[j];
    }
    const float ig = sigm(g4[0]);
    const float fg = sigm(g4[1]);
    const float gg = tanhf_(g4[2]);
    const float og = sigm(g4[3]);
    ci = fg * ci + ig * gg;
    hi = og * tanhf_(ci);
    if (l == 0) out[b * LDN + s] = hi;
  }
}

extern "C" void kernel_launch(void* const* d_in, const int* in_sizes, int n_in,
                              void* d_out, int out_size, void* d_ws, size_t ws_size,
                              hipStream_t stream) {
  (void)in_sizes; (void)n_in; (void)out_size; (void)d_ws; (void)ws_size;
  const float* ipq   = (const float*)d_in[0];
  const float* lblp  = (const float*)d_in[1];
  const float* e_h   = (const float*)d_in[2];
  const float* e_w   = (const float*)d_in[3];
  const float* e_m   = (const float*)d_in[4];
  const float* e_y   = (const float*)d_in[5];
  const float* Wi_w  = (const float*)d_in[6];
  const float* Wi_b  = (const float*)d_in[7];
  const float* We_w  = (const float*)d_in[8];
  const float* Vd_w  = (const float*)d_in[9];
  const float* Vd_b  = (const float*)d_in[10];
  const float* eWih  = (const float*)d_in[11];
  const float* eWhh  = (const float*)d_in[12];
  const float* ebih  = (const float*)d_in[13];
  const float* ebhh  = (const float*)d_in[14];
  const float* Wd_w  = (const float*)d_in[15];
  const float* Wd_b  = (const float*)d_in[16];
  const float* Wd2_w = (const float*)d_in[17];
  const float* Vdt_w = (const float*)d_in[18];
  const float* Vdt_b = (const float*)d_in[19];
  const float* dWih  = (const float*)d_in[20];
  const float* dWhh  = (const float*)d_in[21];
  const float* dbih  = (const float*)d_in[22];
  const float* dbhh  = (const float*)d_in[23];
  const int* itime   = (const int*)d_in[24];
  float* out = (float*)d_out;

  stattn_kernel<<<dim3(BB), dim3(64), 0, stream>>>(
      ipq, lblp, e_h, e_w, e_m, e_y, Wi_w, Wi_b, We_w, Vd_w, Vd_b,
      eWih, eWhh, ebih, ebhh, Wd_w, Wd_b, Wd2_w, Vdt_w, Vdt_b,
      dWih, dWhh, dbih, dbhh, itime, out);
}

// Round 3
// 4057.502 us; speedup vs baseline: 5.6339x; 5.6339x over previous
//
#include <hip/hip_runtime.h>

#define BB   8192
#define LEN  40
#define LDN  12
#define PQN  237
#define INN  256
#define HN   64
#define BT   16                 // batch tile per encoder block
#define ENC_BLOCKS (BB / BT)    // 512

typedef unsigned int  u32;
typedef unsigned short u16;

__device__ __forceinline__ float bf2f(u16 u){ return __uint_as_float(((u32)u) << 16); }
__device__ __forceinline__ u16 f2bf(float f){
  u32 x = __float_as_uint(f);
  x += 0x7fffu + ((x >> 16) & 1u);
  return (u16)(x >> 16);
}
__device__ __forceinline__ float sigm(float x){
  return 1.0f / (1.0f + exp2f(-1.44269504f * x));
}
__device__ __forceinline__ float tanhf_(float x){
  x = fminf(15.0f, fmaxf(-15.0f, x));
  float e = exp2f(2.88539008f * x);
  return (e - 1.0f) / (e + 1.0f);
}
__device__ __forceinline__ float dot4(float4 w, float4 a){
  return w.x*a.x + w.y*a.y + w.z*a.z + w.w*a.w;
}

// ---------------- encoder: Bt=16 batch elements per 256-thread block -------
// Thread roles per phase (LDS-synchronized):
//  ph1: thread i loads feature i for each bb             (coalesced)
//  ph2: thread (r=tid&63, g=tid>>6) -> u[r] for bb in {4g..4g+3}
//  ph3: thread i -> score element i for all 16 bb; block softmax-sum
//  ph4: thread r -> gate row r for all 16 bb; then (d=tid&63,g) updates h,c
__global__ __launch_bounds__(256) void enc_kernel(
    const float* __restrict__ ipq,    // (B,LE,PQ)
    const float* __restrict__ e_h, const float* __restrict__ e_w,
    const float* __restrict__ e_m, const float* __restrict__ e_y,
    const float* __restrict__ Wi_w,   // (64,256)
    const float* __restrict__ Wi_b,   // (64)
    const float* __restrict__ We_w,   // (64,128)
    const float* __restrict__ Vd_w,   // (256,64)
    const float* __restrict__ Vd_b,   // (256)
    const float* __restrict__ eWih,   // (256,256)
    const float* __restrict__ eWhh,   // (256,64)
    const float* __restrict__ ebih, const float* __restrict__ ebhh,
    const int* __restrict__ itime,    // (B,LE,4)
    u16* __restrict__ mid)            // (B,LE,64) bf16 workspace
{
  __shared__ __attribute__((aligned(16))) float XG[BT * INN]; // x_t, reused as gates G[4][BT][64]
  __shared__ __attribute__((aligned(16))) float P [BT * INN]; // x_in
  __shared__ __attribute__((aligned(16))) float U [BT * HN];
  __shared__ __attribute__((aligned(16))) float Hs[BT * HN];
  __shared__ __attribute__((aligned(16))) float Cs[BT * HN];
  __shared__ float Wred[BT * 4];                               // per-wave softmax partials

  const int b0   = blockIdx.x * BT;
  const int tid  = threadIdx.x;
  const int lane = tid & 63;
  const int wv   = tid >> 6;

  for (int i = tid; i < BT * HN; i += 256) { Hs[i] = 0.0f; Cs[i] = 0.0f; }
  __syncthreads();

  for (int t = 0; t < LEN; ++t) {
    // ---- phase 1: assemble x_t for 16 batches ----
    for (int bb = 0; bb < BT; ++bb) {
      const int b = b0 + bb;
      float v;
      if (tid < PQN) {
        v = ipq[(b * LEN + t) * PQN + tid];
      } else {
        const int* it = itime + (b * LEN + t) * 4;
        const int o = tid - PQN;
        if      (o < 5 ) v = e_h[it[0] * 5 + o];
        else if (o < 8 ) v = e_w[it[1] * 3 + (o - 5)];
        else if (o < 12) v = e_m[it[2] * 4 + (o - 8)];
        else             v = e_y[it[3] * 7 + (o - 12)];
      }
      XG[bb * INN + tid] = v;
    }
    __syncthreads();

    // ---- phase 2: u = tanh(Wi@x + We@[h;c] + b) for 4 batches/thread ----
    {
      const int r = lane;
      const int bb0 = wv * 4;
      float a0 = Wi_b[r], a1 = a0, a2 = a0, a3 = a0;
      const float4* wr = (const float4*)(Wi_w + r * INN);
      const float4* x0 = (const float4*)(XG + (bb0 + 0) * INN);
      const float4* x1 = (const float4*)(XG + (bb0 + 1) * INN);
      const float4* x2 = (const float4*)(XG + (bb0 + 2) * INN);
      const float4* x3 = (const float4*)(XG + (bb0 + 3) * INN);
      #pragma unroll 4
      for (int k = 0; k < 64; ++k) {
        float4 w = wr[k];
        a0 += dot4(w, x0[k]); a1 += dot4(w, x1[k]);
        a2 += dot4(w, x2[k]); a3 += dot4(w, x3[k]);
      }
      const float4* wr2 = (const float4*)(We_w + r * (2 * HN));
      const float4* h0 = (const float4*)(Hs + (bb0 + 0) * HN);
      const float4* h1 = (const float4*)(Hs + (bb0 + 1) * HN);
      const float4* h2 = (const float4*)(Hs + (bb0 + 2) * HN);
      const float4* h3 = (const float4*)(Hs + (bb0 + 3) * HN);
      #pragma unroll 4
      for (int k = 0; k < 16; ++k) {
        float4 w = wr2[k];
        a0 += dot4(w, h0[k]); a1 += dot4(w, h1[k]);
        a2 += dot4(w, h2[k]); a3 += dot4(w, h3[k]);
      }
      const float4* c0 = (const float4*)(Cs + (bb0 + 0) * HN);
      const float4* c1 = (const float4*)(Cs + (bb0 + 1) * HN);
      const float4* c2 = (const float4*)(Cs + (bb0 + 2) * HN);
      const float4* c3 = (const float4*)(Cs + (bb0 + 3) * HN);
      #pragma unroll 4
      for (int k = 0; k < 16; ++k) {
        float4 w = wr2[16 + k];
        a0 += dot4(w, c0[k]); a1 += dot4(w, c1[k]);
        a2 += dot4(w, c2[k]); a3 += dot4(w, c3[k]);
      }
      U[(bb0 + 0) * HN + r] = tanhf_(a0);
      U[(bb0 + 1) * HN + r] = tanhf_(a1);
      U[(bb0 + 2) * HN + r] = tanhf_(a2);
      U[(bb0 + 3) * HN + r] = tanhf_(a3);
    }
    __syncthreads();

    // ---- phase 3: scores + softmax (no max-subtract: |score| <~ 2.5) ----
    {
      float e[BT];
      #pragma unroll
      for (int bb = 0; bb < BT; ++bb) e[bb] = Vd_b[tid];
      const float4* wr = (const float4*)(Vd_w + tid * HN);
      #pragma unroll 4
      for (int k = 0; k < 16; ++k) {
        float4 w = wr[k];
        #pragma unroll
        for (int bb = 0; bb < BT; ++bb)
          e[bb] += dot4(w, ((const float4*)(U + bb * HN))[k]);
      }
      #pragma unroll
      for (int bb = 0; bb < BT; ++bb) e[bb] = exp2f(e[bb] * 1.44269504f);
      // wave-level sum per bb, then cross-wave via LDS
      #pragma unroll
      for (int bb = 0; bb < BT; ++bb) {
        float s = e[bb];
        #pragma unroll
        for (int off = 32; off >= 1; off >>= 1) s += __shfl_xor(s, off, 64);
        if (lane == 0) Wred[bb * 4 + wv] = s;
      }
      __syncthreads();
      #pragma unroll
      for (int bb = 0; bb < BT; ++bb) {
        const float inv = 1.0f / (Wred[bb*4+0] + Wred[bb*4+1] + Wred[bb*4+2] + Wred[bb*4+3]);
        P[bb * INN + tid] = XG[bb * INN + tid] * e[bb] * inv;
      }
    }
    __syncthreads();

    // ---- phase 4: gates = eWih@p + eWhh@h + b ; row tid, 16 batches ----
    {
      float acc[BT];
      const float bi = ebih[tid] + ebhh[tid];
      #pragma unroll
      for (int bb = 0; bb < BT; ++bb) acc[bb] = bi;
      const float4* wr = (const float4*)(eWih + tid * INN);
      #pragma unroll 2
      for (int k = 0; k < 64; ++k) {
        float4 w = wr[k];
        #pragma unroll
        for (int bb = 0; bb < BT; ++bb)
          acc[bb] += dot4(w, ((const float4*)(P + bb * INN))[k]);
      }
      const float4* wr2 = (const float4*)(eWhh + tid * HN);
      #pragma unroll 2
      for (int k = 0; k < 16; ++k) {
        float4 w = wr2[k];
        #pragma unroll
        for (int bb = 0; bb < BT; ++bb)
          acc[bb] += dot4(w, ((const float4*)(Hs + bb * HN))[k]);
      }
      // write gates into XG as G[gate][bb][d]; gate=wv, d=lane (X dead now)
      #pragma unroll
      for (int bb = 0; bb < BT; ++bb)
        XG[(wv * BT + bb) * HN + lane] = acc[bb];
    }
    __syncthreads();

    // ---- cell update: d=lane, bb in {4*wv..4*wv+3} ----
    {
      const int d = lane;
      #pragma unroll
      for (int jj = 0; jj < 4; ++jj) {
        const int bb = wv * 4 + jj;
        const float gi = XG[(0 * BT + bb) * HN + d];
        const float gf = XG[(1 * BT + bb) * HN + d];
        const float gg = XG[(2 * BT + bb) * HN + d];
        const float go = XG[(3 * BT + bb) * HN + d];
        float c = Cs[bb * HN + d];
        c = sigm(gf) * c + sigm(gi) * tanhf_(gg);
        const float h = sigm(go) * tanhf_(c);
        Hs[bb * HN + d] = h;
        Cs[bb * HN + d] = c;
        mid[((b0 + bb) * LEN + t) * HN + d] = f2bf(h);
      }
    }
    __syncthreads();
  }
}

// ---------------- decoder: one wave per batch element ----------------------
__global__ __launch_bounds__(64) void dec_kernel(
    const u16* __restrict__ mid,      // (B,LE,64) bf16
    const float* __restrict__ lblp,   // (B,LE)
    const float* __restrict__ Wd_w,   // (64,64)
    const float* __restrict__ Wd_b,   // (64)
    const float* __restrict__ Wd2_w,  // (64,2)
    const float* __restrict__ Vdt_w,  // (1,64)
    const float* __restrict__ Vdt_b,  // (1)
    const float* __restrict__ dWih,   // (4,65)
    const float* __restrict__ dWhh,   // (4,1)
    const float* __restrict__ dbih, const float* __restrict__ dbhh,
    float* __restrict__ out)          // (B,LD)
{
  __shared__ __attribute__((aligned(16))) float ms[LEN * HN];
  __shared__ __attribute__((aligned(16))) float wm[LEN * HN];

  const int b = blockIdx.x;
  const int l = threadIdx.x;

  for (int t = 0; t < LEN; ++t)
    ms[t * HN + l] = bf2f(mid[(b * LEN + t) * HN + l]);
  __syncthreads();

  // wd_mid[t][l] = Wd_w[l,:] @ mid[t,:] + Wd_b[l]
  {
    float wrow[64];
    const float4* wr = (const float4*)(Wd_w + l * HN);
    #pragma unroll
    for (int k4 = 0; k4 < 16; ++k4) {
      float4 w = wr[k4];
      wrow[4*k4+0] = w.x; wrow[4*k4+1] = w.y; wrow[4*k4+2] = w.z; wrow[4*k4+3] = w.w;
    }
    const float wb = Wd_b[l];
    for (int t = 0; t < LEN; ++t) {
      const float4* mv = (const float4*)(ms + t * HN);
      float acc = wb;
      #pragma unroll
      for (int k4 = 0; k4 < 16; ++k4) {
        float4 mm = mv[k4];
        acc += wrow[4*k4+0]*mm.x + wrow[4*k4+1]*mm.y + wrow[4*k4+2]*mm.z + wrow[4*k4+3]*mm.w;
      }
      wm[t * HN + l] = acc;
    }
  }
  __syncthreads();

  const float dpin = lblp[b * LEN + (LEN - 1)];
  const float w20 = Wd2_w[2 * l];
  const float w21 = Wd2_w[2 * l + 1];
  const float vdt = Vdt_w[l];
  const float vdtb = Vdt_b[0];
  float wih[4], wxx[4], whh[4], bi4[4], bh4[4];
  #pragma unroll
  for (int j = 0; j < 4; ++j) {
    wih[j] = dWih[j * 65 + l];
    wxx[j] = dWih[j * 65 + 64];
    whh[j] = dWhh[j];
    bi4[j] = dbih[j];
    bh4[j] = dbhh[j];
  }

  float hi = 0.0f, ci = 0.0f;
  for (int s = 0; s < LDN; ++s) {
    const float q = w20 * hi + w21 * ci;
    float ctx = 0.0f;
    for (int t = 0; t < LEN; ++t) {
      float e = tanhf_(q + wm[t * HN + l]) * vdt;
      #pragma unroll
      for (int off = 32; off >= 1; off >>= 1) e += __shfl_xor(e, off, 64);
      ctx += (e + vdtb) * ms[t * HN + l];
    }
    float g4[4];
    #pragma unroll
    for (int j = 0; j < 4; ++j) {
      float p = wih[j] * ctx;
      #pragma unroll
      for (int off = 32; off >= 1; off >>= 1) p += __shfl_xor(p, off, 64);
      g4[j] = p + wxx[j] * dpin + bi4[j] + whh[j] * hi + bh4[j];
    }
    ci = sigm(g4[1]) * ci + sigm(g4[0]) * tanhf_(g4[2]);
    hi = sigm(g4[3]) * tanhf_(ci);
    if (l == 0) out[b * LDN + s] = hi;
  }
}

extern "C" void kernel_launch(void* const* d_in, const int* in_sizes, int n_in,
                              void* d_out, int out_size, void* d_ws, size_t ws_size,
                              hipStream_t stream) {
  (void)in_sizes; (void)n_in; (void)out_size; (void)ws_size;
  const float* ipq   = (const float*)d_in[0];
  const float* lblp  = (const float*)d_in[1];
  const float* e_h   = (const float*)d_in[2];
  const float* e_w   = (const float*)d_in[3];
  const float* e_m   = (const float*)d_in[4];
  const float* e_y   = (const float*)d_in[5];
  const float* Wi_w  = (const float*)d_in[6];
  const float* Wi_b  = (const float*)d_in[7];
  const float* We_w  = (const float*)d_in[8];
  const float* Vd_w  = (const float*)d_in[9];
  const float* Vd_b  = (const float*)d_in[10];
  const float* eWih  = (const float*)d_in[11];
  const float* eWhh  = (const float*)d_in[12];
  const float* ebih  = (const float*)d_in[13];
  const float* ebhh  = (const float*)d_in[14];
  const float* Wd_w  = (const float*)d_in[15];
  const float* Wd_b  = (const float*)d_in[16];
  const float* Wd2_w = (const float*)d_in[17];
  const float* Vdt_w = (const float*)d_in[18];
  const float* Vdt_b = (const float*)d_in[19];
  const float* dWih  = (const float*)d_in[20];
  const float* dWhh  = (const float*)d_in[21];
  const float* dbih  = (const float*)d_in[22];
  const float* dbhh  = (const float*)d_in[23];
  const int* itime   = (const int*)d_in[24];
  float* out = (float*)d_out;
  u16* mid = (u16*)d_ws;   // 8192*40*64 bf16 = 41.9 MB

  enc_kernel<<<dim3(ENC_BLOCKS), dim3(256), 0, stream>>>(
      ipq, e_h, e_w, e_m, e_y, Wi_w, Wi_b, We_w, Vd_w, Vd_b,
      eWih, eWhh, ebih, ebhh, itime, mid);
  dec_kernel<<<dim3(BB), dim3(64), 0, stream>>>(
      mid, lblp, Wd_w, Wd_b, Wd2_w, Vdt_w, Vdt_b,
      dWih, dWhh, dbih, dbhh, out);
}

// Round 4
// 1913.070 us; speedup vs baseline: 11.9491x; 2.1209x over previous
//
#include <hip/hip_runtime.h>

#define BB   8192
#define LEN  40
#define LDN  12
#define PQN  237
#define INN  256
#define HN   64
#define BT   16
#define ENC_BLOCKS (BB / BT)    // 512

typedef unsigned int  u32;
typedef unsigned short u16;
typedef _Float16 f16;
typedef f16  half8 __attribute__((ext_vector_type(8)));
typedef f16  f16x4 __attribute__((ext_vector_type(4)));
typedef float f32x4 __attribute__((ext_vector_type(4)));

#define XS 272   // row stride for X/P (256+16), 16B-aligned
#define HS 80    // row stride for U/H/C (64+16)

// weight offsets (f16 elements) inside converted-weight buffer
#define OFF_WI   0
#define OFF_WE   16384
#define OFF_VD   24576
#define OFF_WIH  40960
#define OFF_WHH  106496
#define W_TOTAL  122880

__device__ __forceinline__ float sigm(float x){
  return 1.0f / (1.0f + exp2f(-1.44269504f * x));
}
__device__ __forceinline__ float tanhf_(float x){
  x = fminf(15.0f, fmaxf(-15.0f, x));
  float e = exp2f(2.88539008f * x);
  return (e - 1.0f) / (e + 1.0f);
}
__device__ __forceinline__ float dot4(float4 w, float4 a){
  return w.x*a.x + w.y*a.y + w.z*a.z + w.w*a.w;
}

// ---------------- weight f32 -> f16 conversion (once per launch) -----------
__global__ __launch_bounds__(256) void conv_w(
    const float* __restrict__ Wi, const float* __restrict__ We,
    const float* __restrict__ Vd, const float* __restrict__ Wih,
    const float* __restrict__ Whh, f16* __restrict__ dst)
{
  int i = blockIdx.x * 256 + threadIdx.x;
  if (i >= W_TOTAL) return;
  float v;
  if      (i < OFF_WE)  v = Wi [i - OFF_WI ];
  else if (i < OFF_VD)  v = We [i - OFF_WE ];
  else if (i < OFF_WIH) v = Vd [i - OFF_VD ];
  else if (i < OFF_WHH) v = Wih[i - OFF_WIH];
  else                  v = Whh[i - OFF_WHH];
  dst[i] = (f16)v;
}

// ---------------- encoder: MFMA, BT=16 batches / 256-thread block ----------
// MFMA 16x16x32 f16 layouts (HW-verified mapping):
//   A (weights, M x K): lane holds A[m=lane&15][k=kt*32+quad*8+j], j=0..7
//   B (acts,  K x N):   lane holds B[k=kt*32+quad*8+j][n=lane&15]
//   D (M x N):          reg r holds D[m=quad*4+r][n=lane&15]
// Wave w owns row-tiles {w, w+4, w+8, w+12} of 256-row GEMMs (tile rt=w+4i
// lands in gate section i for the LSTM -> cell update fully in registers).
__global__ __launch_bounds__(256) void enc_mfma(
    const float* __restrict__ ipq,    // (B,LE,PQ)
    const float* __restrict__ e_h, const float* __restrict__ e_w,
    const float* __restrict__ e_m, const float* __restrict__ e_y,
    const float* __restrict__ Wi_b,   // (64)
    const float* __restrict__ Vd_b,   // (256)
    const float* __restrict__ ebih, const float* __restrict__ ebhh, // (256)
    const f16*  __restrict__ wAll,    // converted weights
    const int*  __restrict__ itime,   // (B,LE,4)
    f16* __restrict__ mid)            // (B,LE,64) f16
{
  __shared__ __attribute__((aligned(16))) f16 Xl[BT * XS];
  __shared__ __attribute__((aligned(16))) f16 Pl[BT * XS];
  __shared__ __attribute__((aligned(16))) f16 Ul[BT * HS];
  __shared__ __attribute__((aligned(16))) f16 Hl[BT * HS];
  __shared__ __attribute__((aligned(16))) f16 Cl[BT * HS];
  __shared__ float Sred[64];

  const f16* wWi  = wAll + OFF_WI;
  const f16* wWe  = wAll + OFF_WE;
  const f16* wVd  = wAll + OFF_VD;
  const f16* wWih = wAll + OFF_WIH;
  const f16* wWhh = wAll + OFF_WHH;

  const int tid  = threadIdx.x;
  const int w    = tid >> 6;        // wave id 0..3
  const int lane = tid & 63;
  const int nl   = lane & 15;       // n (batch) index
  const int q    = lane >> 4;       // quad
  const int b0   = blockIdx.x * BT;

  for (int i = tid; i < BT * HS; i += 256) { Hl[i] = (f16)0.f; Cl[i] = (f16)0.f; }
  float creg[4] = {0.f, 0.f, 0.f, 0.f};

  // loop-invariant per-thread biases
  const int d0 = w * 16 + q * 4;    // base hidden-dim row this thread owns
  float wib[4], vdb[16], ebs[16];
  #pragma unroll
  for (int r = 0; r < 4; ++r) wib[r] = Wi_b[d0 + r];
  #pragma unroll
  for (int i = 0; i < 4; ++i)
    #pragma unroll
    for (int r = 0; r < 4; ++r) {
      vdb[i*4+r] = Vd_b[(w + 4*i) * 16 + q * 4 + r];
      ebs[i*4+r] = ebih[i * 64 + d0 + r] + ebhh[i * 64 + d0 + r];
    }
  __syncthreads();

  for (int t = 0; t < LEN; ++t) {
    // ---- phase 1: assemble x_t (f16) for 16 batches ----
    for (int bb = 0; bb < BT; ++bb) {
      const int b = b0 + bb;
      float v;
      if (tid < PQN) {
        v = ipq[(b * LEN + t) * PQN + tid];
      } else {
        const int* it = itime + (b * LEN + t) * 4;
        const int o = tid - PQN;
        if      (o < 5 ) v = e_h[it[0] * 5 + o];
        else if (o < 8 ) v = e_w[it[1] * 3 + (o - 5)];
        else if (o < 12) v = e_m[it[2] * 4 + (o - 8)];
        else             v = e_y[it[3] * 7 + (o - 12)];
      }
      Xl[bb * XS + tid] = (f16)v;
    }
    __syncthreads();

    // ---- phase 2: u = tanh(Wi@X + We@[H;C] + b)  (M=64: rt = w) ----
    {
      f32x4 acc = {0.f, 0.f, 0.f, 0.f};
      const f16* xb = &Xl[nl * XS];
      const f16* wr = wWi + (w * 16 + nl) * 256;
      #pragma unroll
      for (int kt = 0; kt < 8; ++kt) {
        half8 a = *(const half8*)(wr + kt * 32 + q * 8);
        half8 b = *(const half8*)(xb + kt * 32 + q * 8);
        acc = __builtin_amdgcn_mfma_f32_16x16x32_f16(a, b, acc, 0, 0, 0);
      }
      const f16* hb = &Hl[nl * HS];
      const f16* cb = &Cl[nl * HS];
      const f16* wr2 = wWe + (w * 16 + nl) * 128;
      #pragma unroll
      for (int kt = 0; kt < 2; ++kt) {
        half8 a = *(const half8*)(wr2 + kt * 32 + q * 8);
        half8 b = *(const half8*)(hb + kt * 32 + q * 8);
        acc = __builtin_amdgcn_mfma_f32_16x16x32_f16(a, b, acc, 0, 0, 0);
      }
      #pragma unroll
      for (int kt = 0; kt < 2; ++kt) {
        half8 a = *(const half8*)(wr2 + 64 + kt * 32 + q * 8);
        half8 b = *(const half8*)(cb + kt * 32 + q * 8);
        acc = __builtin_amdgcn_mfma_f32_16x16x32_f16(a, b, acc, 0, 0, 0);
      }
      f16x4 uv;
      #pragma unroll
      for (int r = 0; r < 4; ++r) uv[r] = (f16)tanhf_(acc[r] + wib[r]);
      *(f16x4*)(&Ul[nl * HS + d0]) = uv;   // U[k=d0+r][n=nl]
    }
    __syncthreads();

    // ---- phase 3: scores (256x16) = Vd@U + b; softmax; P = X * smax ----
    float ee[16];
    {
      const f16* ub = &Ul[nl * HS];
      #pragma unroll
      for (int i = 0; i < 4; ++i) {
        f32x4 acc = {0.f, 0.f, 0.f, 0.f};
        const f16* wr = wVd + ((w + 4*i) * 16 + nl) * 64;
        #pragma unroll
        for (int kt = 0; kt < 2; ++kt) {
          half8 a = *(const half8*)(wr + kt * 32 + q * 8);
          half8 b = *(const half8*)(ub + kt * 32 + q * 8);
          acc = __builtin_amdgcn_mfma_f32_16x16x32_f16(a, b, acc, 0, 0, 0);
        }
        #pragma unroll
        for (int r = 0; r < 4; ++r)
          ee[i*4+r] = exp2f((acc[r] + vdb[i*4+r]) * 1.44269504f);
      }
      float s = 0.f;
      #pragma unroll
      for (int j = 0; j < 16; ++j) s += ee[j];
      s += __shfl_xor(s, 16, 64);
      s += __shfl_xor(s, 32, 64);            // sum over lanes sharing nl
      if (lane < 16) Sred[w * 16 + lane] = s;
    }
    __syncthreads();
    {
      const float inv = 1.0f / (Sred[nl] + Sred[16 + nl] + Sred[32 + nl] + Sred[48 + nl]);
      #pragma unroll
      for (int i = 0; i < 4; ++i)
        #pragma unroll
        for (int r = 0; r < 4; ++r) {
          const int k = (w + 4*i) * 16 + q * 4 + r;
          Pl[nl * XS + k] = (f16)((float)Xl[nl * XS + k] * ee[i*4+r] * inv);
        }
    }
    __syncthreads();

    // ---- phase 4: gates (256x16) = Wih@P + Whh@H; LSTM update ----
    {
      f32x4 g[4];
      #pragma unroll
      for (int i = 0; i < 4; ++i) g[i] = (f32x4){0.f, 0.f, 0.f, 0.f};
      const f16* pb = &Pl[nl * XS];
      #pragma unroll
      for (int kt = 0; kt < 8; ++kt) {
        half8 b = *(const half8*)(pb + kt * 32 + q * 8);
        #pragma unroll
        for (int i = 0; i < 4; ++i) {
          half8 a = *(const half8*)(wWih + ((w + 4*i) * 16 + nl) * 256 + kt * 32 + q * 8);
          g[i] = __builtin_amdgcn_mfma_f32_16x16x32_f16(a, b, g[i], 0, 0, 0);
        }
      }
      const f16* hb = &Hl[nl * HS];
      #pragma unroll
      for (int kt = 0; kt < 2; ++kt) {
        half8 b = *(const half8*)(hb + kt * 32 + q * 8);
        #pragma unroll
        for (int i = 0; i < 4; ++i) {
          half8 a = *(const half8*)(wWhh + ((w + 4*i) * 16 + nl) * 64 + kt * 32 + q * 8);
          g[i] = __builtin_amdgcn_mfma_f32_16x16x32_f16(a, b, g[i], 0, 0, 0);
        }
      }
      __syncthreads();   // all waves done reading Pl/Hl before H/C overwrite

      f16x4 hv, cv;
      #pragma unroll
      for (int r = 0; r < 4; ++r) {
        const float gi = g[0][r] + ebs[0 + r];
        const float gf = g[1][r] + ebs[4 + r];
        const float gg = g[2][r] + ebs[8 + r];
        const float go = g[3][r] + ebs[12 + r];
        float c = sigm(gf) * creg[r] + sigm(gi) * tanhf_(gg);
        creg[r] = c;
        const float h = sigm(go) * tanhf_(c);
        hv[r] = (f16)h; cv[r] = (f16)c;
      }
      *(f16x4*)(&Hl[nl * HS + d0]) = hv;
      *(f16x4*)(&Cl[nl * HS + d0]) = cv;
      *(f16x4*)(&mid[((b0 + nl) * LEN + t) * HN + d0]) = hv;
    }
    __syncthreads();
  }
}

// ---------------- decoder: one wave per batch element ----------------------
__global__ __launch_bounds__(64) void dec_kernel(
    const f16* __restrict__ mid,      // (B,LE,64) f16
    const float* __restrict__ lblp,   // (B,LE)
    const float* __restrict__ Wd_w,   // (64,64)
    const float* __restrict__ Wd_b,   // (64)
    const float* __restrict__ Wd2_w,  // (64,2)
    const float* __restrict__ Vdt_w,  // (1,64)
    const float* __restrict__ Vdt_b,  // (1)
    const float* __restrict__ dWih,   // (4,65)
    const float* __restrict__ dWhh,   // (4,1)
    const float* __restrict__ dbih, const float* __restrict__ dbhh,
    float* __restrict__ out)          // (B,LD)
{
  __shared__ __attribute__((aligned(16))) float ms[LEN * HN];
  __shared__ __attribute__((aligned(16))) float wm[LEN * HN];

  const int b = blockIdx.x;
  const int l = threadIdx.x;

  for (int t = 0; t < LEN; ++t)
    ms[t * HN + l] = (float)mid[(b * LEN + t) * HN + l];
  __syncthreads();

  {
    float wrow[64];
    const float4* wr = (const float4*)(Wd_w + l * HN);
    #pragma unroll
    for (int k4 = 0; k4 < 16; ++k4) {
      float4 w = wr[k4];
      wrow[4*k4+0] = w.x; wrow[4*k4+1] = w.y; wrow[4*k4+2] = w.z; wrow[4*k4+3] = w.w;
    }
    const float wb = Wd_b[l];
    for (int t = 0; t < LEN; ++t) {
      const float4* mv = (const float4*)(ms + t * HN);
      float acc = wb;
      #pragma unroll
      for (int k4 = 0; k4 < 16; ++k4) {
        float4 mm = mv[k4];
        acc += wrow[4*k4+0]*mm.x + wrow[4*k4+1]*mm.y + wrow[4*k4+2]*mm.z + wrow[4*k4+3]*mm.w;
      }
      wm[t * HN + l] = acc;
    }
  }
  __syncthreads();

  const float dpin = lblp[b * LEN + (LEN - 1)];
  const float w20 = Wd2_w[2 * l];
  const float w21 = Wd2_w[2 * l + 1];
  const float vdt = Vdt_w[l];
  const float vdtb = Vdt_b[0];
  float wih[4], wxx[4], whh[4], bi4[4], bh4[4];
  #pragma unroll
  for (int j = 0; j < 4; ++j) {
    wih[j] = dWih[j * 65 + l];
    wxx[j] = dWih[j * 65 + 64];
    whh[j] = dWhh[j];
    bi4[j] = dbih[j];
    bh4[j] = dbhh[j];
  }

  float hi = 0.0f, ci = 0.0f;
  for (int s = 0; s < LDN; ++s) {
    const float q = w20 * hi + w21 * ci;
    float ctx = 0.0f;
    for (int t = 0; t < LEN; ++t) {
      float e = tanhf_(q + wm[t * HN + l]) * vdt;
      #pragma unroll
      for (int off = 32; off >= 1; off >>= 1) e += __shfl_xor(e, off, 64);
      ctx += (e + vdtb) * ms[t * HN + l];
    }
    float g4[4];
    #pragma unroll
    for (int j = 0; j < 4; ++j) {
      float p = wih[j] * ctx;
      #pragma unroll
      for (int off = 32; off >= 1; off >>= 1) p += __shfl_xor(p, off, 64);
      g4[j] = p + wxx[j] * dpin + bi4[j] + whh[j] * hi + bh4[j];
    }
    ci = sigm(g4[1]) * ci + sigm(g4[0]) * tanhf_(g4[2]);
    hi = sigm(g4[3]) * tanhf_(ci);
    if (l == 0) out[b * LDN + s] = hi;
  }
}

extern "C" void kernel_launch(void* const* d_in, const int* in_sizes, int n_in,
                              void* d_out, int out_size, void* d_ws, size_t ws_size,
                              hipStream_t stream) {
  (void)in_sizes; (void)n_in; (void)out_size; (void)ws_size;
  const float* ipq   = (const float*)d_in[0];
  const float* lblp  = (const float*)d_in[1];
  const float* e_h   = (const float*)d_in[2];
  const float* e_w   = (const float*)d_in[3];
  const float* e_m   = (const float*)d_in[4];
  const float* e_y   = (const float*)d_in[5];
  const float* Wi_w  = (const float*)d_in[6];
  const float* Wi_b  = (const float*)d_in[7];
  const float* We_w  = (const float*)d_in[8];
  const float* Vd_w  = (const float*)d_in[9];
  const float* Vd_b  = (const float*)d_in[10];
  const float* eWih  = (const float*)d_in[11];
  const float* eWhh  = (const float*)d_in[12];
  const float* ebih  = (const float*)d_in[13];
  const float* ebhh  = (const float*)d_in[14];
  const float* Wd_w  = (const float*)d_in[15];
  const float* Wd_b  = (const float*)d_in[16];
  const float* Wd2_w = (const float*)d_in[17];
  const float* Vdt_w = (const float*)d_in[18];
  const float* Vdt_b = (const float*)d_in[19];
  const float* dWih  = (const float*)d_in[20];
  const float* dWhh  = (const float*)d_in[21];
  const float* dbih  = (const float*)d_in[22];
  const float* dbhh  = (const float*)d_in[23];
  const int* itime   = (const int*)d_in[24];
  float* out = (float*)d_out;

  f16* mid  = (f16*)d_ws;                                  // 41.9 MB
  f16* wcvt = (f16*)((char*)d_ws + (size_t)BB * LEN * HN * 2);  // 240 KB

  conv_w<<<dim3((W_TOTAL + 255) / 256), dim3(256), 0, stream>>>(
      Wi_w, We_w, Vd_w, eWih, eWhh, wcvt);
  enc_mfma<<<dim3(ENC_BLOCKS), dim3(256), 0, stream>>>(
      ipq, e_h, e_w, e_m, e_y, Wi_b, Vd_b, ebih, ebhh, wcvt, itime, mid);
  dec_kernel<<<dim3(BB), dim3(64), 0, stream>>>(
      mid, lblp, Wd_w, Wd_b, Wd2_w, Vdt_w, Vdt_b,
      dWih, dWhh, dbih, dbhh, out);
}

// Round 5
// 1729.009 us; speedup vs baseline: 13.2211x; 1.1065x over previous
//
#include <hip/hip_runtime.h>

#define BB   8192
#define LEN  40
#define LDN  12
#define PQN  237
#define INN  256
#define HN   64
#define BT   16
#define ENC_BLOCKS (BB / BT)    // 512
#define DW   4                  // decoder batches per block
#define DEC_BLOCKS (BB / DW)    // 2048

typedef unsigned int  u32;
typedef unsigned short u16;
typedef _Float16 f16;
typedef f16  half8 __attribute__((ext_vector_type(8)));
typedef f16  f16x4 __attribute__((ext_vector_type(4)));
typedef float f32x4 __attribute__((ext_vector_type(4)));

#define XS 264   // X/P row stride (f16): 132 dw -> (nl*132/4+..)%8 spreads, 2-way max
#define HS 72    // U/H/C row stride (f16): 36 dw -> 2-way max

// weight offsets (f16 elements) in converted buffer
#define OFF_WI   0
#define OFF_WE   16384
#define OFF_VD   24576
#define OFF_WIH  40960
#define OFF_WHH  106496
#define OFF_WD   122880
#define W_TOTAL  126976

__device__ __forceinline__ float sigm(float x){
  return 1.0f / (1.0f + exp2f(-1.44269504f * x));
}
__device__ __forceinline__ float tanhf_(float x){
  x = fminf(15.0f, fmaxf(-15.0f, x));
  float e = exp2f(2.88539008f * x);
  return (e - 1.0f) / (e + 1.0f);
}

// ---------------- weight f32 -> f16 conversion (once per launch) -----------
__global__ __launch_bounds__(256) void conv_w(
    const float* __restrict__ Wi, const float* __restrict__ We,
    const float* __restrict__ Vd, const float* __restrict__ Wih,
    const float* __restrict__ Whh, const float* __restrict__ Wd,
    f16* __restrict__ dst)
{
  int i = blockIdx.x * 256 + threadIdx.x;
  if (i >= W_TOTAL) return;
  float v;
  if      (i < OFF_WE)  v = Wi [i - OFF_WI ];
  else if (i < OFF_VD)  v = We [i - OFF_WE ];
  else if (i < OFF_WIH) v = Vd [i - OFF_VD ];
  else if (i < OFF_WHH) v = Wih[i - OFF_WIH];
  else if (i < OFF_WD)  v = Whh[i - OFF_WHH];
  else                  v = Wd [i - OFF_WD ];
  dst[i] = (f16)v;
}

// ---------------- encoder: MFMA, all weights register-resident -------------
// 16x16x32 f16 MFMA layouts: A lane holds A[m=lane&15][k=q*8+j];
// B lane holds B[k=q*8+j][n=lane&15]; D reg r = D[m=q*4+r][n=lane&15].
// Wave w owns 256-row GEMM row-tiles {w,w+4,w+8,w+12} (tile w+4i = gate i,
// same d-rows -> LSTM update fully in registers). Weight slice/wave = 248
// VGPRs/lane, preloaded once; K-loop reads no global weights.
__global__ __launch_bounds__(256, 1) void enc_mfma(
    const float* __restrict__ ipq,
    const float* __restrict__ e_h, const float* __restrict__ e_w,
    const float* __restrict__ e_m, const float* __restrict__ e_y,
    const float* __restrict__ Wi_b,   // (64)
    const float* __restrict__ Vd_b,   // (256)
    const float* __restrict__ ebih, const float* __restrict__ ebhh, // (256)
    const float* __restrict__ Wd_b,   // (64)
    const f16*  __restrict__ wAll,
    const int*  __restrict__ itime,
    f16* __restrict__ mid,            // (B,LE,64)
    f16* __restrict__ wmid)           // (B,LE,64)  Wd@mid + b
{
  __shared__ __attribute__((aligned(16))) f16 Xl[BT * XS];
  __shared__ __attribute__((aligned(16))) f16 Pl[BT * XS];
  __shared__ __attribute__((aligned(16))) f16 Ul[BT * HS];
  __shared__ __attribute__((aligned(16))) f16 Hl[BT * HS];
  __shared__ __attribute__((aligned(16))) f16 Cl[BT * HS];
  __shared__ float Sred[64];

  const int tid  = threadIdx.x;
  const int w    = tid >> 6;
  const int lane = tid & 63;
  const int nl   = lane & 15;
  const int q    = lane >> 4;
  const int b0   = blockIdx.x * BT;
  const int d0   = w * 16 + q * 4;

  // ---- preload weight fragments into registers (one time) ----
  half8 wif[8], wef[4], vdf[4][2], whf[4][8], whhf[4][2], wdf[2];
  {
    const f16* pw = wAll + OFF_WI + (w * 16 + nl) * 256 + q * 8;
    #pragma unroll
    for (int kt = 0; kt < 8; ++kt) wif[kt] = *(const half8*)(pw + kt * 32);
    const f16* pe = wAll + OFF_WE + (w * 16 + nl) * 128 + q * 8;
    #pragma unroll
    for (int kt = 0; kt < 4; ++kt) wef[kt] = *(const half8*)(pe + kt * 32);
    #pragma unroll
    for (int i = 0; i < 4; ++i) {
      const f16* pv = wAll + OFF_VD + ((w + 4*i) * 16 + nl) * 64 + q * 8;
      #pragma unroll
      for (int kt = 0; kt < 2; ++kt) vdf[i][kt] = *(const half8*)(pv + kt * 32);
      const f16* ph = wAll + OFF_WIH + ((w + 4*i) * 16 + nl) * 256 + q * 8;
      #pragma unroll
      for (int kt = 0; kt < 8; ++kt) whf[i][kt] = *(const half8*)(ph + kt * 32);
      const f16* pq = wAll + OFF_WHH + ((w + 4*i) * 16 + nl) * 64 + q * 8;
      #pragma unroll
      for (int kt = 0; kt < 2; ++kt) whhf[i][kt] = *(const half8*)(pq + kt * 32);
    }
    const f16* pd = wAll + OFF_WD + (w * 16 + nl) * 64 + q * 8;
    #pragma unroll
    for (int kt = 0; kt < 2; ++kt) wdf[kt] = *(const half8*)(pd + kt * 32);
  }

  float wib[4], vdb[16], ebs[16], wdb[4];
  #pragma unroll
  for (int r = 0; r < 4; ++r) { wib[r] = Wi_b[d0 + r]; wdb[r] = Wd_b[d0 + r]; }
  #pragma unroll
  for (int i = 0; i < 4; ++i)
    #pragma unroll
    for (int r = 0; r < 4; ++r) {
      vdb[i*4+r] = Vd_b[(w + 4*i) * 16 + q * 4 + r];
      ebs[i*4+r] = ebih[i * 64 + d0 + r] + ebhh[i * 64 + d0 + r];
    }

  for (int i = tid; i < BT * HS; i += 256) { Hl[i] = (f16)0.f; Cl[i] = (f16)0.f; }
  float creg[4] = {0.f, 0.f, 0.f, 0.f};
  __syncthreads();

  for (int t = 0; t < LEN; ++t) {
    // ---- phase 1: assemble x_t ----
    for (int bb = 0; bb < BT; ++bb) {
      const int b = b0 + bb;
      float v;
      if (tid < PQN) {
        v = ipq[(b * LEN + t) * PQN + tid];
      } else {
        const int* it = itime + (b * LEN + t) * 4;
        const int o = tid - PQN;
        if      (o < 5 ) v = e_h[it[0] * 5 + o];
        else if (o < 8 ) v = e_w[it[1] * 3 + (o - 5)];
        else if (o < 12) v = e_m[it[2] * 4 + (o - 8)];
        else             v = e_y[it[3] * 7 + (o - 12)];
      }
      Xl[bb * XS + tid] = (f16)v;
    }
    __syncthreads();

    // ---- phase 2: u = tanh(Wi@X + We@[H;C] + b) ----
    {
      f32x4 acc = {0.f, 0.f, 0.f, 0.f};
      const f16* xb = &Xl[nl * XS + q * 8];
      #pragma unroll
      for (int kt = 0; kt < 8; ++kt)
        acc = __builtin_amdgcn_mfma_f32_16x16x32_f16(wif[kt], *(const half8*)(xb + kt * 32), acc, 0, 0, 0);
      const f16* hb = &Hl[nl * HS + q * 8];
      const f16* cb = &Cl[nl * HS + q * 8];
      #pragma unroll
      for (int kt = 0; kt < 2; ++kt)
        acc = __builtin_amdgcn_mfma_f32_16x16x32_f16(wef[kt], *(const half8*)(hb + kt * 32), acc, 0, 0, 0);
      #pragma unroll
      for (int kt = 0; kt < 2; ++kt)
        acc = __builtin_amdgcn_mfma_f32_16x16x32_f16(wef[2 + kt], *(const half8*)(cb + kt * 32), acc, 0, 0, 0);
      f16x4 uv;
      #pragma unroll
      for (int r = 0; r < 4; ++r) uv[r] = (f16)tanhf_(acc[r] + wib[r]);
      *(f16x4*)(&Ul[nl * HS + d0]) = uv;
    }
    __syncthreads();

    // ---- phase 3: scores = Vd@U + b; softmax (no max-sub); P = X*smax ----
    float ee[16];
    {
      const f16* ub = &Ul[nl * HS + q * 8];
      half8 u0 = *(const half8*)(ub);
      half8 u1 = *(const half8*)(ub + 32);
      #pragma unroll
      for (int i = 0; i < 4; ++i) {
        f32x4 acc = {0.f, 0.f, 0.f, 0.f};
        acc = __builtin_amdgcn_mfma_f32_16x16x32_f16(vdf[i][0], u0, acc, 0, 0, 0);
        acc = __builtin_amdgcn_mfma_f32_16x16x32_f16(vdf[i][1], u1, acc, 0, 0, 0);
        #pragma unroll
        for (int r = 0; r < 4; ++r)
          ee[i*4+r] = exp2f((acc[r] + vdb[i*4+r]) * 1.44269504f);
      }
      float s = 0.f;
      #pragma unroll
      for (int j = 0; j < 16; ++j) s += ee[j];
      s += __shfl_xor(s, 16, 64);
      s += __shfl_xor(s, 32, 64);
      if (lane < 16) Sred[w * 16 + lane] = s;
    }
    __syncthreads();
    {
      const float inv = 1.0f / (Sred[nl] + Sred[16 + nl] + Sred[32 + nl] + Sred[48 + nl]);
      #pragma unroll
      for (int i = 0; i < 4; ++i) {
        const int k = (w + 4*i) * 16 + q * 4;
        f16x4 pv;
        #pragma unroll
        for (int r = 0; r < 4; ++r)
          pv[r] = (f16)((float)Xl[nl * XS + k + r] * ee[i*4+r] * inv);
        *(f16x4*)(&Pl[nl * XS + k]) = pv;
      }
    }
    __syncthreads();

    // ---- phase 4: gates = Wih@P + Whh@H; LSTM update in registers ----
    {
      f32x4 g[4];
      #pragma unroll
      for (int i = 0; i < 4; ++i) g[i] = (f32x4){0.f, 0.f, 0.f, 0.f};
      const f16* pb = &Pl[nl * XS + q * 8];
      #pragma unroll
      for (int kt = 0; kt < 8; ++kt) {
        half8 b = *(const half8*)(pb + kt * 32);
        #pragma unroll
        for (int i = 0; i < 4; ++i)
          g[i] = __builtin_amdgcn_mfma_f32_16x16x32_f16(whf[i][kt], b, g[i], 0, 0, 0);
      }
      const f16* hb = &Hl[nl * HS + q * 8];
      #pragma unroll
      for (int kt = 0; kt < 2; ++kt) {
        half8 b = *(const half8*)(hb + kt * 32);
        #pragma unroll
        for (int i = 0; i < 4; ++i)
          g[i] = __builtin_amdgcn_mfma_f32_16x16x32_f16(whhf[i][kt], b, g[i], 0, 0, 0);
      }
      __syncthreads();   // all waves done reading Pl/Hl before H/C overwrite

      f16x4 hv, cv;
      #pragma unroll
      for (int r = 0; r < 4; ++r) {
        const float gi = g[0][r] + ebs[0 + r];
        const float gf = g[1][r] + ebs[4 + r];
        const float gg = g[2][r] + ebs[8 + r];
        const float go = g[3][r] + ebs[12 + r];
        float c = sigm(gf) * creg[r] + sigm(gi) * tanhf_(gg);
        creg[r] = c;
        const float h = sigm(go) * tanhf_(c);
        hv[r] = (f16)h; cv[r] = (f16)c;
      }
      *(f16x4*)(&Hl[nl * HS + d0]) = hv;
      *(f16x4*)(&Cl[nl * HS + d0]) = cv;
      *(f16x4*)(&mid[((b0 + nl) * LEN + t) * HN + d0]) = hv;
    }
    __syncthreads();

    // ---- wm phase: wmid_t = Wd@h_t + b (reads updated Hl; no extra sync:
    //      next phase-1 touches only Xl, phase-2 reads Hl unchanged) ----
    {
      const f16* hb = &Hl[nl * HS + q * 8];
      f32x4 acc = {0.f, 0.f, 0.f, 0.f};
      acc = __builtin_amdgcn_mfma_f32_16x16x32_f16(wdf[0], *(const half8*)(hb), acc, 0, 0, 0);
      acc = __builtin_amdgcn_mfma_f32_16x16x32_f16(wdf[1], *(const half8*)(hb + 32), acc, 0, 0, 0);
      f16x4 wv4;
      #pragma unroll
      for (int r = 0; r < 4; ++r) wv4[r] = (f16)(acc[r] + wdb[r]);
      *(f16x4*)(&wmid[((b0 + nl) * LEN + t) * HN + d0]) = wv4;
    }
  }
}

// ---------------- decoder: 4 batches (1 wave each) per 256-thread block ----
#define MTS 56   // msT row stride (f16): d*28dw -> (7d)%8 spreads, optimal
#define WMS 56   // wm  row stride (f16): t*28dw -> (7t)%8 spreads

__global__ __launch_bounds__(256) void dec_kernel(
    const f16* __restrict__ mid,      // (B,LE,64)
    const f16* __restrict__ wmid,     // (B,LE,64)  Wd@mid + b
    const float* __restrict__ lblp,
    const float* __restrict__ Wd2_w,  // (64,2)
    const float* __restrict__ Vdt_w,  // (1,64)
    const float* __restrict__ Vdt_b,  // (1)
    const float* __restrict__ dWih,   // (4,65)
    const float* __restrict__ dWhh,   // (4,1)
    const float* __restrict__ dbih, const float* __restrict__ dbhh,
    float* __restrict__ out)          // (B,LD)
{
  __shared__ __attribute__((aligned(16))) f16  msT[DW][HN * MTS];  // [d][t]
  __shared__ __attribute__((aligned(16))) f16  wml[DW][LEN * WMS]; // [t][d]
  __shared__ __attribute__((aligned(16))) float qv[DW][HN];
  __shared__ __attribute__((aligned(16))) float Sv[DW][48];
  __shared__ __attribute__((aligned(16))) float vs[HN];

  const int w    = threadIdx.x >> 6;
  const int lane = threadIdx.x & 63;
  const int b    = blockIdx.x * DW + w;

  for (int t = 0; t < LEN; ++t) {
    msT[w][lane * MTS + t] = mid [(b * LEN + t) * HN + lane];
    wml[w][t * WMS + lane] = wmid[(b * LEN + t) * HN + lane];
  }
  if (threadIdx.x < HN) vs[threadIdx.x] = Vdt_w[threadIdx.x];
  __syncthreads();   // vs visible to all waves

  const float dpin = lblp[b * LEN + (LEN - 1)];
  const float w20 = Wd2_w[2 * lane];
  const float w21 = Wd2_w[2 * lane + 1];
  const float vdtb = Vdt_b[0];
  float wih[4], wxx[4], whh[4], bb4[4];
  #pragma unroll
  for (int j = 0; j < 4; ++j) {
    wih[j] = dWih[j * 65 + lane];
    wxx[j] = dWih[j * 65 + 64];
    whh[j] = dWhh[j];
    bb4[j] = dbih[j] + dbhh[j];
  }

  float hi = 0.0f, ci = 0.0f;
  for (int s = 0; s < LDN; ++s) {
    qv[w][lane] = w20 * hi + w21 * ci;   // same-wave LDS RAW: compiler waits

    // ---- scores: lane = t ----
    if (lane < LEN) {
      const f16* wrow = &wml[w][lane * WMS];
      float acc = 0.f;
      #pragma unroll
      for (int k8 = 0; k8 < 8; ++k8) {
        float4 qa = *(const float4*)&qv[w][k8 * 8];
        float4 qb = *(const float4*)&qv[w][k8 * 8 + 4];
        float4 va = *(const float4*)&vs[k8 * 8];
        float4 vb = *(const float4*)&vs[k8 * 8 + 4];
        half8 wv = *(const half8*)(wrow + k8 * 8);
        acc += tanhf_(qa.x + (float)wv[0]) * va.x
             + tanhf_(qa.y + (float)wv[1]) * va.y
             + tanhf_(qa.z + (float)wv[2]) * va.z
             + tanhf_(qa.w + (float)wv[3]) * va.w
             + tanhf_(qb.x + (float)wv[4]) * vb.x
             + tanhf_(qb.y + (float)wv[5]) * vb.y
             + tanhf_(qb.z + (float)wv[6]) * vb.z
             + tanhf_(qb.w + (float)wv[7]) * vb.w;
      }
      Sv[w][lane] = acc + vdtb;
    }

    // ---- ctx: lane = d ----
    float ctx = 0.f;
    {
      const f16* mrow = &msT[w][lane * MTS];
      #pragma unroll
      for (int t8 = 0; t8 < 5; ++t8) {
        float4 sa = *(const float4*)&Sv[w][t8 * 8];
        float4 sb = *(const float4*)&Sv[w][t8 * 8 + 4];
        half8 mv = *(const half8*)(mrow + t8 * 8);
        ctx += sa.x * (float)mv[0] + sa.y * (float)mv[1]
             + sa.z * (float)mv[2] + sa.w * (float)mv[3]
             + sb.x * (float)mv[4] + sb.y * (float)mv[5]
             + sb.z * (float)mv[6] + sb.w * (float)mv[7];
      }
    }

    // ---- gates: 4 full-wave reductions over d ----
    float g4[4];
    #pragma unroll
    for (int j = 0; j < 4; ++j) {
      float p = wih[j] * ctx;
      #pragma unroll
      for (int off = 32; off >= 1; off >>= 1) p += __shfl_xor(p, off, 64);
      g4[j] = p + wxx[j] * dpin + bb4[j] + whh[j] * hi;
    }
    ci = sigm(g4[1]) * ci + sigm(g4[0]) * tanhf_(g4[2]);
    hi = sigm(g4[3]) * tanhf_(ci);
    if (lane == 0) out[b * LDN + s] = hi;
  }
}

extern "C" void kernel_launch(void* const* d_in, const int* in_sizes, int n_in,
                              void* d_out, int out_size, void* d_ws, size_t ws_size,
                              hipStream_t stream) {
  (void)in_sizes; (void)n_in; (void)out_size; (void)ws_size;
  const float* ipq   = (const float*)d_in[0];
  const float* lblp  = (const float*)d_in[1];
  const float* e_h   = (const float*)d_in[2];
  const float* e_w   = (const float*)d_in[3];
  const float* e_m   = (const float*)d_in[4];
  const float* e_y   = (const float*)d_in[5];
  const float* Wi_w  = (const float*)d_in[6];
  const float* Wi_b  = (const float*)d_in[7];
  const float* We_w  = (const float*)d_in[8];
  const float* Vd_w  = (const float*)d_in[9];
  const float* Vd_b  = (const float*)d_in[10];
  const float* eWih  = (const float*)d_in[11];
  const float* eWhh  = (const float*)d_in[12];
  const float* ebih  = (const float*)d_in[13];
  const float* ebhh  = (const float*)d_in[14];
  const float* Wd_w  = (const float*)d_in[15];
  const float* Wd_b  = (const float*)d_in[16];
  const float* Wd2_w = (const float*)d_in[17];
  const float* Vdt_w = (const float*)d_in[18];
  const float* Vdt_b = (const float*)d_in[19];
  const float* dWih  = (const float*)d_in[20];
  const float* dWhh  = (const float*)d_in[21];
  const float* dbih  = (const float*)d_in[22];
  const float* dbhh  = (const float*)d_in[23];
  const int* itime   = (const int*)d_in[24];
  float* out = (float*)d_out;

  const size_t midB = (size_t)BB * LEN * HN * 2;   // 41.94 MB
  f16* mid  = (f16*)d_ws;
  f16* wmid = (f16*)((char*)d_ws + midB);
  f16* wcvt = (f16*)((char*)d_ws + 2 * midB);      // +248 KB

  conv_w<<<dim3((W_TOTAL + 255) / 256), dim3(256), 0, stream>>>(
      Wi_w, We_w, Vd_w, eWih, eWhh, Wd_w, wcvt);
  enc_mfma<<<dim3(ENC_BLOCKS), dim3(256), 0, stream>>>(
      ipq, e_h, e_w, e_m, e_y, Wi_b, Vd_b, ebih, ebhh, Wd_b, wcvt, itime,
      mid, wmid);
  dec_kernel<<<dim3(DEC_BLOCKS), dim3(256), 0, stream>>>(
      mid, wmid, lblp, Wd2_w, Vdt_w, Vdt_b, dWih, dWhh, dbih, dbhh, out);
}